// Round 2
// baseline (186.492 us; speedup 1.0000x reference)
//
#include <hip/hip_runtime.h>

typedef short bf16x8 __attribute__((ext_vector_type(8)));
typedef float f32x16 __attribute__((ext_vector_type(16)));

#define DI __device__ __forceinline__

constexpr int BS = 2, CH = 128;
constexpr int NQ = 16384, NM = 4096;
constexpr size_t NX = (size_t)BS * CH * NQ;   // 4,194,304 elements per output

DI float bf2f(ushort u) { unsigned v = ((unsigned)u) << 16; return __builtin_bit_cast(float, v); }
DI ushort f2bf(float f) {
  unsigned u = __builtin_bit_cast(unsigned, f);
  u += 0x7FFFu + ((u >> 16) & 1u);   // RNE
  return (ushort)(u >> 16);
}
// dual-dtype scalar load: f==1 -> buffer is f32, else bf16 ushort
DI float ldany(const void* p, size_t i, int f) {
  return f ? ((const float*)p)[i] : bf2f(((const ushort*)p)[i]);
}

DI f32x16 mfma_bf16(bf16x8 a, bf16x8 b, f32x16 c) {
  return __builtin_amdgcn_mfma_f32_32x32x16_bf16(a, b, c, 0, 0, 0);
}

// ---------------- pass -1: dtype sniff ----------------
// f32 buffer read as bf16 ushorts: even indices are f32 low-mantissa bits ->
// random exponents -> many |v|>1e9 / NaN. True bf16 N(0,1) buffer: none.
// bf16-quantized-but-f32-strided buffer: even ushorts are all zero.
__global__ void k_sniff(const void* __restrict__ x, int* __restrict__ flag) {
  if (threadIdx.x == 0 && blockIdx.x == 0) {
    const ushort* u = (const ushort*)x;
    int garbage = 0, zeros = 0;
    for (int i = 0; i < 256; ++i) {
      float v = bf2f(u[i]);
      if (!(fabsf(v) < 1e9f)) garbage++;           // also true for NaN
      if ((i & 1) == 0 && u[i] == 0) zeros++;
    }
    flag[0] = (garbage >= 8 || zeros >= 100) ? 1 : 0;   // 1 = f32 buffers
  }
}

// ---------------- pass -0.5: canonicalize x to bf16 ----------------
__global__ __launch_bounds__(256) void k_convert(
    const void* __restrict__ x, const int* __restrict__ flag, ushort* __restrict__ xc)
{
  size_t i = ((size_t)blockIdx.x * 256 + threadIdx.x) * 8;
  if (flag[0]) {
    const float* xf = (const float*)x;
    union { uint4 v4; ushort s[8]; } o;
    #pragma unroll
    for (int k = 0; k < 8; ++k) o.s[k] = f2bf(xf[i + k]);
    *(uint4*)(xc + i) = o.v4;
  } else {
    *(uint4*)(xc + i) = *(const uint4*)((const ushort*)x + i);
  }
}

// ---------------- pass 0: weight prep ----------------
// wAllf: rows 0-15 w_theta, 16-31 w_phi, 32-95 w_g (f32)
// bAllf: [0,16) bT, [16,32) bP, [32,96) bG, [96,224) bAG
// wF: A-fragments of w_attn_g for epilogue MFMA: [ot4][ks4][lane64] 8bf16
__global__ __launch_bounds__(256) void k_prep(
    const void* __restrict__ wT, const void* __restrict__ bT,
    const void* __restrict__ wP, const void* __restrict__ bP,
    const void* __restrict__ wG, const void* __restrict__ bG,
    const void* __restrict__ wAG, const void* __restrict__ bAG,
    const int* __restrict__ flag,
    float* __restrict__ wAllf, float* __restrict__ bAllf, uint4* __restrict__ wF)
{
  int t = threadIdx.x;
  int f = flag[0];
  if (blockIdx.x == 0) {
    for (int i = t; i < 16 * 128; i += 256) wAllf[i]        = ldany(wT, i, f);
    for (int i = t; i < 16 * 128; i += 256) wAllf[2048 + i] = ldany(wP, i, f);
    for (int i = t; i < 64 * 128; i += 256) wAllf[4096 + i] = ldany(wG, i, f);
    if (t < 16)  bAllf[t]       = ldany(bT, t, f);
    if (t < 16)  bAllf[16 + t]  = ldany(bP, t, f);
    if (t < 64)  bAllf[32 + t]  = ldany(bG, t, f);
    if (t < 128) bAllf[96 + t]  = ldany(bAG, t, f);
  } else {
    int idx = (blockIdx.x - 1) * 256 + t;  // 0..1023
    int lane = idx & 63, ks = (idx >> 6) & 3, ot = idx >> 8;
    size_t src = (size_t)(ot * 32 + (lane & 31)) * 64 + ks * 16 + (lane >> 5) * 8;
    union { uint4 v4; ushort s[8]; } o;
    #pragma unroll
    for (int j = 0; j < 8; ++j) o.s[j] = f2bf(ldany(wAG, src + j, f));
    wF[idx] = o.v4;
  }
}

// ---------------- pass 1: projections ----------------
// theta[b][q][16] bf16 (tanh), phi[b][m][16] bf16 (maxpool pre-act then tanh),
// g[b][m][64] f32 (maxpool). One thread per q; 2x2 pool via wave shuffles
// (a 64-lane wave covers exactly a 2x32 (w,h) patch).
__global__ __launch_bounds__(256) void k_proj(
    const ushort* __restrict__ xc, const float* __restrict__ wAllf, const float* __restrict__ bAllf,
    ushort* __restrict__ theta, ushort* __restrict__ phi, float* __restrict__ g)
{
  int b = blockIdx.y;
  int v = blockIdx.x >> 6;        // 0: theta+phi, 1: g[0:32), 2: g[32:64)
  int qt = blockIdx.x & 63;
  int t = threadIdx.x;
  int q = qt * 256 + t;

  __shared__ float wsh[32][128];
  for (int i = t; i < 32 * 128; i += 256) wsh[i >> 7][i & 127] = wAllf[v * 4096 + i];
  __syncthreads();

  const ushort* xb = xc + (size_t)b * CH * NQ + q;
  float acc[32];
  #pragma unroll
  for (int o = 0; o < 32; ++o) acc[o] = 0.f;

  for (int c0 = 0; c0 < CH; c0 += 8) {
    float xv[8];
    #pragma unroll
    for (int k = 0; k < 8; ++k) xv[k] = bf2f(xb[(size_t)(c0 + k) * NQ]);
    #pragma unroll
    for (int o = 0; o < 32; ++o) {
      #pragma unroll
      for (int k = 0; k < 8; ++k) acc[o] = fmaf(xv[k], wsh[o][c0 + k], acc[o]);
    }
  }

  int hh = q & 31, ww = (q >> 5) & 31, nn = q >> 10;
  int m = nn * 256 + (ww >> 1) * 16 + (hh >> 1);
  bool pool_lane = ((t & 1) == 0) && ((t & 32) == 0);

  if (v == 0) {
    union { uint4 v4[2]; ushort s[16]; } th;
    #pragma unroll
    for (int o = 0; o < 16; ++o) th.s[o] = f2bf(tanhf(acc[o] + bAllf[o]));
    uint4* dst = (uint4*)(theta + ((size_t)b * NQ + q) * 16);
    dst[0] = th.v4[0]; dst[1] = th.v4[1];

    float pp[16];
    #pragma unroll
    for (int o = 0; o < 16; ++o) {
      float z = acc[16 + o] + bAllf[16 + o];
      z = fmaxf(z, __shfl_xor(z, 1, 64));
      z = fmaxf(z, __shfl_xor(z, 32, 64));
      pp[o] = z;
    }
    if (pool_lane) {
      union { uint4 v4[2]; ushort s[16]; } ph;
      #pragma unroll
      for (int o = 0; o < 16; ++o) ph.s[o] = f2bf(tanhf(pp[o]));
      uint4* pdst = (uint4*)(phi + ((size_t)b * NM + m) * 16);
      pdst[0] = ph.v4[0]; pdst[1] = ph.v4[1];
    }
  } else {
    int cbase = (v - 1) * 32;
    float pg[32];
    #pragma unroll
    for (int o = 0; o < 32; ++o) {
      float z = acc[o] + bAllf[32 + cbase + o];
      z = fmaxf(z, __shfl_xor(z, 1, 64));
      z = fmaxf(z, __shfl_xor(z, 32, 64));
      pg[o] = z;
    }
    if (pool_lane) {
      float* gd = g + ((size_t)b * NM + m) * 64 + cbase;
      #pragma unroll
      for (int k = 0; k < 8; ++k) {
        float4 f4 = make_float4(pg[4 * k], pg[4 * k + 1], pg[4 * k + 2], pg[4 * k + 3]);
        *(float4*)(gd + 4 * k) = f4;
      }
    }
  }
}

// ---------------- pass 2: softmax denominator partials ----------------
// softmax is over the QUERY axis: denom[b][m] = sum_q exp(theta[q].phi[m]).
// |S| <= 16 so no max-subtraction needed. Deterministic 8-way q-split.
__global__ __launch_bounds__(256) void k_denom(
    const ushort* __restrict__ theta, const ushort* __restrict__ phi,
    float* __restrict__ partial)
{
  int b = blockIdx.z, qs = blockIdx.y;
  int w = threadIdx.x >> 6;
  int l = threadIdx.x & 63, lr = l & 31, lh = l >> 5;
  int m0 = blockIdx.x * 128 + w * 32;

  bf16x8 pB = __builtin_bit_cast(bf16x8, *(const uint4*)(phi + ((size_t)b * NM + m0 + lr) * 16 + lh * 8));

  float s = 0.f;
  int qb = qs * 2048;
  for (int qq = 0; qq < 2048; qq += 32) {
    bf16x8 tA = __builtin_bit_cast(bf16x8, *(const uint4*)(theta + ((size_t)b * NQ + qb + qq + lr) * 16 + lh * 8));
    f32x16 S;
    #pragma unroll
    for (int i = 0; i < 16; ++i) S[i] = 0.f;
    S = mfma_bf16(tA, pB, S);
    #pragma unroll
    for (int r = 0; r < 16; ++r) s += __expf(S[r]);
  }
  s += __shfl_xor(s, 32, 64);          // combine the two row-halves (same column)
  if (l < 32) partial[((size_t)b * 8 + qs) * NM + m0 + lr] = s;
}

// ---------------- pass 2.5: scaled-g B-fragments ----------------
// gs[m][c] = g[m][c]/denom[m], stored pre-swizzled as PV B-fragments:
// gsF[b][ms][ct][lane] j-th bf16 = gs[ms*16 + (lane>>5)*8 + j][ct*32 + (lane&31)]
__global__ __launch_bounds__(256) void k_gsf(
    const float* __restrict__ g, const float* __restrict__ partial,
    uint4* __restrict__ gsF)
{
  int t = threadIdx.x;
  int b = blockIdx.x >> 7;
  int mBase = (blockIdx.x & 127) * 32;

  __shared__ float dinv[32];
  if (t < 32) {
    int m = mBase + t;
    float s = 0.f;
    #pragma unroll
    for (int p = 0; p < 8; ++p) s += partial[((size_t)b * 8 + p) * NM + m];
    dinv[t] = 1.f / s;
  }
  __syncthreads();

  int lane = t & 63, ct = (t >> 6) & 1, msh = t >> 7;
  int mloc = msh * 16 + (lane >> 5) * 8;
  int c = ct * 32 + (lane & 31);
  union { uint4 v4; ushort s[8]; } outv;
  #pragma unroll
  for (int j = 0; j < 8; ++j) {
    int ml = mloc + j;
    float val = g[((size_t)b * NM + mBase + ml) * 64 + c] * dinv[ml];
    outv.s[j] = f2bf(val);
  }
  gsF[(size_t)blockIdx.x * 256 + t] = outv.v4;
}

// ---------------- pass 3: fused attention + output ----------------
// Block = 32 q rows, 4 waves m-split. Per wave/iter: S = mfma(theta,phi) (K=16 exact),
// exp -> bf16 -> per-wave private LDS P tile ([32][40] pad), 4 PV mfma accumulations.
// Epilogue: LDS-reduce the 4 m-partials, final 128x64 projection as mfma with
// o-rows/q-cols so stores coalesce. Output stores are dual-dtype.
__global__ __launch_bounds__(256) void k_attn(
    const ushort* __restrict__ theta, const ushort* __restrict__ phi,
    const uint4* __restrict__ gsF, const uint4* __restrict__ wF,
    const float* __restrict__ bAllf, const ushort* __restrict__ xc,
    const void* __restrict__ gamma, const int* __restrict__ flag,
    void* __restrict__ out_base)
{
  int b = blockIdx.y;
  int q0 = blockIdx.x * 32;
  int t = threadIdx.x;
  int w = t >> 6, l = t & 63, lr = l & 31, lh = l >> 5;

  __shared__ __align__(16) ushort Plds[4][32][40];
  __shared__ float agPart[4][32][65];
  __shared__ __align__(16) ushort agF[32][80];

  bf16x8 tA = __builtin_bit_cast(bf16x8, *(const uint4*)(theta + ((size_t)b * NQ + q0 + lr) * 16 + lh * 8));

  f32x16 acc0, acc1;
  #pragma unroll
  for (int i = 0; i < 16; ++i) { acc0[i] = 0.f; acc1[i] = 0.f; }

  for (int it = 0; it < 32; ++it) {
    int m0 = w * 32 + it * 128;
    bf16x8 pB = __builtin_bit_cast(bf16x8, *(const uint4*)(phi + ((size_t)b * NM + m0 + lr) * 16 + lh * 8));
    f32x16 S;
    #pragma unroll
    for (int i = 0; i < 16; ++i) S[i] = 0.f;
    S = mfma_bf16(tA, pB, S);

    int ms0 = m0 >> 4;
    size_t gbase = ((size_t)b * 256 + ms0) * 128;
    uint4 g00 = gsF[gbase + l];
    uint4 g01 = gsF[gbase + 64 + l];
    uint4 g10 = gsF[gbase + 128 + l];
    uint4 g11 = gsF[gbase + 192 + l];

    #pragma unroll
    for (int r = 0; r < 16; ++r) {
      int qq = (r & 3) + 8 * (r >> 2) + 4 * lh;   // C/D row map (32x32)
      Plds[w][qq][lr] = f2bf(__expf(S[r]));       // col = lane&31
    }
    __syncthreads();   // correctness-first; within-wave LDS dep (A/B-remove later)

    bf16x8 pa0 = __builtin_bit_cast(bf16x8, *(const uint4*)&Plds[w][lr][lh * 8]);
    bf16x8 pa1 = __builtin_bit_cast(bf16x8, *(const uint4*)&Plds[w][lr][16 + lh * 8]);

    acc0 = mfma_bf16(pa0, __builtin_bit_cast(bf16x8, g00), acc0);
    acc1 = mfma_bf16(pa0, __builtin_bit_cast(bf16x8, g01), acc1);
    acc0 = mfma_bf16(pa1, __builtin_bit_cast(bf16x8, g10), acc0);
    acc1 = mfma_bf16(pa1, __builtin_bit_cast(bf16x8, g11), acc1);
  }

  #pragma unroll
  for (int r = 0; r < 16; ++r) {
    int qq = (r & 3) + 8 * (r >> 2) + 4 * lh;
    agPart[w][qq][lr] = acc0[r];
    agPart[w][qq][32 + lr] = acc1[r];
  }
  __syncthreads();

  #pragma unroll
  for (int jj = 0; jj < 8; ++jj) {
    int c = w * 16 + lh * 8 + jj;
    float vsum = agPart[0][lr][c] + agPart[1][lr][c] + agPart[2][lr][c] + agPart[3][lr][c];
    agF[lr][c] = f2bf(vsum);
  }
  __syncthreads();

  f32x16 oacc;
  #pragma unroll
  for (int i = 0; i < 16; ++i) oacc[i] = 0.f;
  #pragma unroll
  for (int ks = 0; ks < 4; ++ks) {
    bf16x8 aw = __builtin_bit_cast(bf16x8, wF[(w * 4 + ks) * 64 + l]);
    bf16x8 bg = __builtin_bit_cast(bf16x8, *(const uint4*)&agF[lr][ks * 16 + lh * 8]);
    oacc = mfma_bf16(aw, bg, oacc);   // rows = o, cols = q  -> coalesced stores
  }

  int mode = flag[0];
  float ga = ldany(gamma, 0, mode);
  float alpha = 1.f / (1.f + __expf(-ga));

  if (mode) {
    float* o0 = (float*)out_base;
    float* o1 = o0 + NX;
    #pragma unroll
    for (int r = 0; r < 16; ++r) {
      int o = w * 32 + (r & 3) + 8 * (r >> 2) + 4 * lh;
      size_t oi = ((size_t)b * CH + o) * NQ + q0 + lr;
      float ag = oacc[r] + bAllf[96 + o];
      float xv = bf2f(xc[oi]);
      o0[oi] = (1.f - alpha) * xv + alpha * ag;
      o1[oi] = ag;
    }
  } else {
    ushort* o0 = (ushort*)out_base;
    ushort* o1 = o0 + NX;
    #pragma unroll
    for (int r = 0; r < 16; ++r) {
      int o = w * 32 + (r & 3) + 8 * (r >> 2) + 4 * lh;
      size_t oi = ((size_t)b * CH + o) * NQ + q0 + lr;
      float ag = oacc[r] + bAllf[96 + o];
      float xv = bf2f(xc[oi]);
      o0[oi] = f2bf((1.f - alpha) * xv + alpha * ag);
      o1[oi] = f2bf(ag);
    }
  }
}

extern "C" void kernel_launch(void* const* d_in, const int* in_sizes, int n_in,
                              void* d_out, int out_size, void* d_ws, size_t ws_size,
                              hipStream_t stream) {
  const void* x    = d_in[0];
  const void* wT   = d_in[1];
  const void* bT   = d_in[2];
  const void* wP   = d_in[3];
  const void* bP   = d_in[4];
  const void* wG   = d_in[5];
  const void* bG   = d_in[6];
  const void* wAG  = d_in[7];
  const void* bAG  = d_in[8];
  const void* gmm  = d_in[9];

  char* ws = (char*)d_ws;
  ushort* theta  = (ushort*)(ws + 0);          // 1 MB
  ushort* phi    = (ushort*)(ws + 1048576);    // 256 KB
  float*  g      = (float*) (ws + 1310720);    // 2 MB
  float*  part   = (float*) (ws + 3407872);    // 256 KB
  uint4*  gsF    = (uint4*) (ws + 3670016);    // 1 MB
  uint4*  wF     = (uint4*) (ws + 4718592);    // 16 KB
  float*  wAllf  = (float*) (ws + 4734976);    // 48 KB
  float*  bAllf  = (float*) (ws + 4784128);    // 1 KB
  int*    flag   = (int*)   (ws + 4785152);    // 4 B
  ushort* xc     = (ushort*)(ws + 4785408);    // 8 MB canonical bf16 x

  k_sniff<<<dim3(1), dim3(64), 0, stream>>>(x, flag);
  k_convert<<<dim3(2048), dim3(256), 0, stream>>>(x, flag, xc);
  k_prep<<<dim3(5), dim3(256), 0, stream>>>(wT, bT, wP, bP, wG, bG, wAG, bAG, flag, wAllf, bAllf, wF);
  k_proj<<<dim3(192, 2), dim3(256), 0, stream>>>(xc, wAllf, bAllf, theta, phi, g);
  k_denom<<<dim3(32, 8, 2), dim3(256), 0, stream>>>(theta, phi, part);
  k_gsf<<<dim3(256), dim3(256), 0, stream>>>(g, part, gsF);
  k_attn<<<dim3(512, 2), dim3(256), 0, stream>>>(theta, phi, gsF, wF, bAllf, xc, gmm, flag, d_out);
}

// Round 3
// 163.990 us; speedup vs baseline: 1.1372x; 1.1372x over previous
//
#include <hip/hip_runtime.h>

typedef short bf16x8 __attribute__((ext_vector_type(8)));
typedef float f32x16 __attribute__((ext_vector_type(16)));

#define DI __device__ __forceinline__

constexpr int BS = 2, CH = 128;
constexpr int NQ = 16384, NM = 4096;
constexpr size_t NX = (size_t)BS * CH * NQ;   // elements per output tensor

DI float bf2f(ushort u) { unsigned v = ((unsigned)u) << 16; return __builtin_bit_cast(float, v); }
DI ushort f2bf(float f) {
  unsigned u = __builtin_bit_cast(unsigned, f);
  u += 0x7FFFu + ((u >> 16) & 1u);   // RNE
  return (ushort)(u >> 16);
}
DI float ldany(const void* p, size_t i, int f) {
  return f ? ((const float*)p)[i] : bf2f(((const ushort*)p)[i]);
}
DI f32x16 mfma_bf16(bf16x8 a, bf16x8 b, f32x16 c) {
  return __builtin_amdgcn_mfma_f32_32x32x16_bf16(a, b, c, 0, 0, 0);
}

// ---------------- dtype sniff ----------------
__global__ void k_sniff(const void* __restrict__ x, int* __restrict__ flag) {
  if (threadIdx.x == 0 && blockIdx.x == 0) {
    const ushort* u = (const ushort*)x;
    int garbage = 0, zeros = 0;
    for (int i = 0; i < 256; ++i) {
      float v = bf2f(u[i]);
      if (!(fabsf(v) < 1e9f)) garbage++;
      if ((i & 1) == 0 && u[i] == 0) zeros++;
    }
    flag[0] = (garbage >= 8 || zeros >= 100) ? 1 : 0;   // 1 = f32 buffers
  }
}

// ---------------- weight prep ----------------
// wAllf rows: [0,16) w_theta, [16,32) w_phi, [32,96) w_g   (f32, row*128+c)
// bAllf: [0,16) bT, [16,32) bP, [32,96) bG, [96,224) bAG
// wF: epilogue A-frags of w_attn_g: [ot4][ks4][lane64] -> 8 bf16
__global__ __launch_bounds__(256) void k_prep(
    const void* __restrict__ wT, const void* __restrict__ bT,
    const void* __restrict__ wP, const void* __restrict__ bP,
    const void* __restrict__ wG, const void* __restrict__ bG,
    const void* __restrict__ wAG, const void* __restrict__ bAG,
    const int* __restrict__ flag,
    float* __restrict__ wAllf, float* __restrict__ bAllf, uint4* __restrict__ wF)
{
  int t = threadIdx.x;
  int f = flag[0];
  if (blockIdx.x == 0) {
    for (int i = t; i < 16 * 128; i += 256) wAllf[i]        = ldany(wT, i, f);
    for (int i = t; i < 16 * 128; i += 256) wAllf[2048 + i] = ldany(wP, i, f);
    for (int i = t; i < 64 * 128; i += 256) wAllf[4096 + i] = ldany(wG, i, f);
    if (t < 16)  bAllf[t]       = ldany(bT, t, f);
    if (t < 16)  bAllf[16 + t]  = ldany(bP, t, f);
    if (t < 64)  bAllf[32 + t]  = ldany(bG, t, f);
    if (t < 128) bAllf[96 + t]  = ldany(bAG, t, f);
  } else {
    int idx = (blockIdx.x - 1) * 256 + t;  // 0..1023
    int lane = idx & 63, ks = (idx >> 6) & 3, ot = idx >> 8;
    size_t src = (size_t)(ot * 32 + (lane & 31)) * 64 + ks * 16 + (lane >> 5) * 8;
    union { uint4 v4; ushort s[8]; } o;
    #pragma unroll
    for (int j = 0; j < 8; ++j) o.s[j] = f2bf(ldany(wAG, src + j, f));
    wF[idx] = o.v4;
  }
}

// ---------------- projections ----------------
// 12 channel-groups of 8 outputs; each thread handles 2 q (an h-pair).
// grp 0-1: theta (tanh, scaled by log2e, bf16 [q][16])
// grp 2-3: phi   (maxpool pre-act, tanh, bf16 [m][16])
// grp 4-11: g    (maxpool, bf16 TRANSPOSED g_t[c][m] for direct PV B-frag loads)
// Weights read with wave-uniform indices -> SGPR loads.
__global__ __launch_bounds__(256) void k_proj(
    const void* __restrict__ x, const int* __restrict__ flag,
    const float* __restrict__ wAllf, const float* __restrict__ bAllf,
    ushort* __restrict__ theta, ushort* __restrict__ phi, ushort* __restrict__ g_t)
{
  int b = blockIdx.y;
  int grp = blockIdx.x >> 5, qt = blockIdx.x & 31;
  int t = threadIdx.x, lane = t & 63, wv = t >> 6;
  int q = qt * 512 + wv * 128 + lane * 2;
  int f = flag[0];
  const float* wp = wAllf + (grp << 10);

  float a0[8], a1[8];
  #pragma unroll
  for (int o = 0; o < 8; ++o) { a0[o] = 0.f; a1[o] = 0.f; }

  size_t xoff = (size_t)b * CH * NQ + q;
  if (f) {
    const float* xf = (const float*)x + xoff;
    for (int c0 = 0; c0 < CH; c0 += 8) {
      float2 xv[8];
      #pragma unroll
      for (int k = 0; k < 8; ++k) xv[k] = *(const float2*)(xf + (size_t)(c0 + k) * NQ);
      #pragma unroll
      for (int o = 0; o < 8; ++o) {
        #pragma unroll
        for (int k = 0; k < 8; ++k) {
          float wgt = wp[o * 128 + c0 + k];
          a0[o] = fmaf(xv[k].x, wgt, a0[o]);
          a1[o] = fmaf(xv[k].y, wgt, a1[o]);
        }
      }
    }
  } else {
    const ushort* xu = (const ushort*)x + xoff;
    for (int c0 = 0; c0 < CH; c0 += 8) {
      float xl[8], xh[8];
      #pragma unroll
      for (int k = 0; k < 8; ++k) {
        uint v = *(const uint*)(xu + (size_t)(c0 + k) * NQ);
        xl[k] = bf2f((ushort)(v & 0xFFFFu));
        xh[k] = bf2f((ushort)(v >> 16));
      }
      #pragma unroll
      for (int o = 0; o < 8; ++o) {
        #pragma unroll
        for (int k = 0; k < 8; ++k) {
          float wgt = wp[o * 128 + c0 + k];
          a0[o] = fmaf(xl[k], wgt, a0[o]);
          a1[o] = fmaf(xh[k], wgt, a1[o]);
        }
      }
    }
  }

  int bb = grp * 8;
  constexpr float L2E = 1.4426950408889634f;

  if (grp < 2) {
    union { uint4 v4; ushort s[8]; } t0, t1;
    #pragma unroll
    for (int o = 0; o < 8; ++o) {
      t0.s[o] = f2bf(tanhf(a0[o] + bAllf[bb + o]) * L2E);
      t1.s[o] = f2bf(tanhf(a1[o] + bAllf[bb + o]) * L2E);
    }
    *(uint4*)(theta + ((size_t)b * NQ + q) * 16 + bb)     = t0.v4;
    *(uint4*)(theta + ((size_t)b * NQ + q + 1) * 16 + bb) = t1.v4;
  } else {
    float z[8];
    #pragma unroll
    for (int o = 0; o < 8; ++o) {
      float m2 = fmaxf(a0[o], a1[o]) + bAllf[bb + o];   // h-pair in-thread
      z[o] = fmaxf(m2, __shfl_xor(m2, 16, 64));          // w-pair across lanes
    }
    if ((lane & 16) == 0) {
      int hh = q & 31, ww = (q >> 5) & 31, nn = q >> 10;
      int m = nn * 256 + (ww >> 1) * 16 + (hh >> 1);
      if (grp < 4) {
        union { uint4 v4; ushort s[8]; } ph;
        #pragma unroll
        for (int o = 0; o < 8; ++o) ph.s[o] = f2bf(tanhf(z[o]));
        *(uint4*)(phi + ((size_t)b * NM + m) * 16 + (bb - 16)) = ph.v4;
      } else {
        int c0 = bb - 32;
        #pragma unroll
        for (int o = 0; o < 8; ++o)
          g_t[((size_t)b * 64 + c0 + o) * NM + m] = f2bf(z[o]);
      }
    }
  }
}

// ---------------- softmax denominator partials ----------------
// denom[b][m] = sum_q exp2(theta_s[q].phi[m]); 16-way deterministic q-split.
__global__ __launch_bounds__(256) void k_denom(
    const ushort* __restrict__ theta, const ushort* __restrict__ phi,
    float* __restrict__ partial)
{
  int b = blockIdx.z, qs = blockIdx.y;
  int w = threadIdx.x >> 6;
  int l = threadIdx.x & 63, lr = l & 31, lh = l >> 5;
  int m0 = blockIdx.x * 128 + w * 32;

  bf16x8 pB = __builtin_bit_cast(bf16x8, *(const uint4*)(phi + ((size_t)b * NM + m0 + lr) * 16 + lh * 8));

  float s = 0.f;
  int qb = qs * 1024;
  for (int qq = 0; qq < 1024; qq += 32) {
    bf16x8 tA = __builtin_bit_cast(bf16x8, *(const uint4*)(theta + ((size_t)b * NQ + qb + qq + lr) * 16 + lh * 8));
    f32x16 S;
    #pragma unroll
    for (int i = 0; i < 16; ++i) S[i] = 0.f;
    S = mfma_bf16(tA, pB, S);
    #pragma unroll
    for (int r = 0; r < 16; ++r) s += exp2f(S[r]);
  }
  s += __shfl_xor(s, 32, 64);
  if (l < 32) partial[(((size_t)b * 16 + qs) << 12) + m0 + lr] = s;
}

// ---------------- denominator reduce ----------------
__global__ __launch_bounds__(256) void k_dinv(
    const float* __restrict__ partial, float* __restrict__ dinv)
{
  int idx = blockIdx.x * 256 + threadIdx.x;   // 8192
  int b = idx >> 12, m = idx & 4095;
  float s = 0.f;
  #pragma unroll
  for (int p = 0; p < 16; ++p) s += partial[(((size_t)b * 16 + p) << 12) + m];
  dinv[idx] = 1.f / s;
}

// ---------------- fused attention + output ----------------
// Block: 64 q, 8 waves = (m-quarter mq) x (q-half qh). No in-loop barriers:
// P tile is wave-private in LDS. P = exp2(S)*dinv[m] folded here (no gsF pass).
__global__ __launch_bounds__(512) void k_attn(
    const ushort* __restrict__ theta, const ushort* __restrict__ phi,
    const ushort* __restrict__ g_t, const float* __restrict__ dinv,
    const uint4* __restrict__ wF, const float* __restrict__ bAllf,
    const void* __restrict__ x, const void* __restrict__ gamma,
    const int* __restrict__ flag, void* __restrict__ out_base)
{
  int b = blockIdx.y;
  int q0 = blockIdx.x * 64;
  int t = threadIdx.x;
  int w = t >> 6, l = t & 63, lr = l & 31, lh = l >> 5;
  int mq = w & 3, qh = w >> 2;

  __shared__ __align__(16) ushort Plds[8][32][40];
  __shared__ float agPart[4][32][65];
  __shared__ __align__(16) ushort agF[32][80];

  int qw = q0 + qh * 32;
  bf16x8 tA = __builtin_bit_cast(bf16x8, *(const uint4*)(theta + ((size_t)b * NQ + qw + lr) * 16 + lh * 8));

  const ushort* gt0 = g_t + ((size_t)b * 64 + lr) * NM;        // ct=0 row
  const ushort* gt1 = gt0 + (size_t)32 * NM;                    // ct=1 row
  const float* dvp = dinv + (size_t)b * NM;

  f32x16 acc0, acc1;
  #pragma unroll
  for (int i = 0; i < 16; ++i) { acc0[i] = 0.f; acc1[i] = 0.f; }

  for (int it = 0; it < 32; ++it) {
    int m0 = mq * 32 + it * 128;
    bf16x8 pB = __builtin_bit_cast(bf16x8, *(const uint4*)(phi + ((size_t)b * NM + m0 + lr) * 16 + lh * 8));
    float dv = dvp[m0 + lr];

    f32x16 S;
    #pragma unroll
    for (int i = 0; i < 16; ++i) S[i] = 0.f;
    S = mfma_bf16(tA, pB, S);

    uint4 g00 = *(const uint4*)(gt0 + m0 + lh * 8);
    uint4 g01 = *(const uint4*)(gt1 + m0 + lh * 8);
    uint4 g10 = *(const uint4*)(gt0 + m0 + 16 + lh * 8);
    uint4 g11 = *(const uint4*)(gt1 + m0 + 16 + lh * 8);

    #pragma unroll
    for (int r = 0; r < 16; ++r) {
      int qq = (r & 3) + 8 * (r >> 2) + 4 * lh;
      Plds[w][qq][lr] = f2bf(exp2f(S[r]) * dv);
    }
    bf16x8 pa0 = __builtin_bit_cast(bf16x8, *(const uint4*)&Plds[w][lr][lh * 8]);
    bf16x8 pa1 = __builtin_bit_cast(bf16x8, *(const uint4*)&Plds[w][lr][16 + lh * 8]);

    acc0 = mfma_bf16(pa0, __builtin_bit_cast(bf16x8, g00), acc0);
    acc1 = mfma_bf16(pa0, __builtin_bit_cast(bf16x8, g01), acc1);
    acc0 = mfma_bf16(pa1, __builtin_bit_cast(bf16x8, g10), acc0);
    acc1 = mfma_bf16(pa1, __builtin_bit_cast(bf16x8, g11), acc1);
  }

  int mode = flag[0];
  float ga = ldany(gamma, 0, mode);
  float alpha = 1.f / (1.f + __expf(-ga));

  #pragma unroll
  for (int h = 0; h < 2; ++h) {
    __syncthreads();
    if (qh == h) {
      #pragma unroll
      for (int r = 0; r < 16; ++r) {
        int qq = (r & 3) + 8 * (r >> 2) + 4 * lh;
        agPart[mq][qq][lr]      = acc0[r];
        agPart[mq][qq][32 + lr] = acc1[r];
      }
    }
    __syncthreads();
    if (t < 256) {
      int w2 = t >> 6, l2 = t & 63, lr2 = l2 & 31, lh2 = l2 >> 5;
      #pragma unroll
      for (int jj = 0; jj < 8; ++jj) {
        int c = w2 * 16 + lh2 * 8 + jj;
        float vsum = agPart[0][lr2][c] + agPart[1][lr2][c] + agPart[2][lr2][c] + agPart[3][lr2][c];
        agF[lr2][c] = f2bf(vsum);
      }
    }
    __syncthreads();
    if (qh == h) {
      f32x16 oacc;
      #pragma unroll
      for (int i = 0; i < 16; ++i) oacc[i] = 0.f;
      #pragma unroll
      for (int ks = 0; ks < 4; ++ks) {
        bf16x8 aw = __builtin_bit_cast(bf16x8, wF[(mq * 4 + ks) * 64 + l]);
        bf16x8 bg = __builtin_bit_cast(bf16x8, *(const uint4*)&agF[lr][ks * 16 + lh * 8]);
        oacc = mfma_bf16(aw, bg, oacc);
      }
      if (mode) {
        float* o0 = (float*)out_base;
        float* o1 = o0 + NX;
        const float* xf = (const float*)x;
        #pragma unroll
        for (int r = 0; r < 16; ++r) {
          int o = mq * 32 + (r & 3) + 8 * (r >> 2) + 4 * lh;
          size_t oi = ((size_t)b * CH + o) * NQ + q0 + h * 32 + lr;
          float ag = oacc[r] + bAllf[96 + o];
          o0[oi] = (1.f - alpha) * xf[oi] + alpha * ag;
          o1[oi] = ag;
        }
      } else {
        ushort* o0 = (ushort*)out_base;
        ushort* o1 = o0 + NX;
        const ushort* xu = (const ushort*)x;
        #pragma unroll
        for (int r = 0; r < 16; ++r) {
          int o = mq * 32 + (r & 3) + 8 * (r >> 2) + 4 * lh;
          size_t oi = ((size_t)b * CH + o) * NQ + q0 + h * 32 + lr;
          float ag = oacc[r] + bAllf[96 + o];
          o0[oi] = f2bf((1.f - alpha) * bf2f(xu[oi]) + alpha * ag);
          o1[oi] = f2bf(ag);
        }
      }
    }
  }
}

extern "C" void kernel_launch(void* const* d_in, const int* in_sizes, int n_in,
                              void* d_out, int out_size, void* d_ws, size_t ws_size,
                              hipStream_t stream) {
  const void* x    = d_in[0];
  const void* wT   = d_in[1];
  const void* bT   = d_in[2];
  const void* wP   = d_in[3];
  const void* bP   = d_in[4];
  const void* wG   = d_in[5];
  const void* bG   = d_in[6];
  const void* wAG  = d_in[7];
  const void* bAG  = d_in[8];
  const void* gmm  = d_in[9];

  char* ws = (char*)d_ws;
  ushort* theta  = (ushort*)(ws + 0);          // 1 MB
  ushort* phi    = (ushort*)(ws + 1048576);    // 256 KB
  ushort* g_t    = (ushort*)(ws + 1310720);    // 1 MB  [b][c][m] bf16
  float*  part   = (float*) (ws + 2359296);    // 512 KB
  float*  dinv   = (float*) (ws + 2883584);    // 32 KB
  uint4*  wF     = (uint4*) (ws + 2916352);    // 16 KB
  float*  wAllf  = (float*) (ws + 2932736);    // 48 KB
  float*  bAllf  = (float*) (ws + 2981888);    // 1 KB
  int*    flag   = (int*)   (ws + 2983936);    // 4 B

  k_sniff<<<dim3(1), dim3(64), 0, stream>>>(x, flag);
  k_prep<<<dim3(5), dim3(256), 0, stream>>>(wT, bT, wP, bP, wG, bG, wAG, bAG, flag, wAllf, bAllf, wF);
  k_proj<<<dim3(384, 2), dim3(256), 0, stream>>>(x, flag, wAllf, bAllf, theta, phi, g_t);
  k_denom<<<dim3(32, 16, 2), dim3(256), 0, stream>>>(theta, phi, part);
  k_dinv<<<dim3(32), dim3(256), 0, stream>>>(part, dinv);
  k_attn<<<dim3(256, 2), dim3(512), 0, stream>>>(theta, phi, g_t, dinv, wF, bAllf, x, gmm, flag, d_out);
}